// Round 7
// baseline (697.532 us; speedup 1.0000x reference)
//
#include <hip/hip_runtime.h>
#include <math.h>

// LDS padding for the wave-FFT buffers: +1 complex slot every 16 keeps all
// three access phases (8*lane+m contiguous, lane+64j strided, q+64p+8m) at
// <=2-way bank aliasing (free on CDNA4).
#define FI(i) ((i) + ((i) >> 4))

__device__ inline float2 cmulf(float2 a, float2 b) {
    return make_float2(a.x * b.x - a.y * b.y, a.x * b.y + a.y * b.x);
}
__device__ inline float2 cadd(float2 a, float2 b) { return make_float2(a.x + b.x, a.y + b.y); }
__device__ inline float2 csub(float2 a, float2 b) { return make_float2(a.x - b.x, a.y - b.y); }

// Complex MAC: a += w * v
__device__ inline void cmac(float2& a, float2 w, float2 v) {
    a.x = fmaf(w.x, v.x, a.x);
    a.x = fmaf(-w.y, v.y, a.x);
    a.y = fmaf(w.x, v.y, a.y);
    a.y = fmaf(w.y, v.x, a.y);
}

// Bijective chunked XCD remap (grid % 8 == 0): hardware bids with equal
// (bid&7) — same XCD under round-robin dispatch — get CONSECUTIVE logical
// indices, so line-sharing neighbor blocks hit the same L2.
__device__ inline int xcd_remap(int bid, int q) {
    return (bid & 7) * q + (bid >> 3);
}

// Wave-local LDS fence: each FFT is owned by ONE wave (private LDS buffer),
// so ordering needs only this wave's LDS ops drained — no __syncthreads.
__device__ inline void wave_fence() {
    asm volatile("s_waitcnt lgkmcnt(0)" ::: "memory");
    __builtin_amdgcn_sched_barrier(0);
}

// rot90: multiply by -i (forward) / +i (inverse).
template <bool INV>
__device__ inline float2 rot90(float2 z) {
    return INV ? make_float2(-z.y, z.x) : make_float2(z.y, -z.x);
}

// In-register 8-point DFT, v[m] = sum_j v_in[j] * exp(-+2*pi*i*j*m/8).
// Verified by hand on delta inputs (j=1, j=2) for both directions.
template <bool INV>
__device__ inline void dft8(float2 v[8]) {
    const float R2 = 0.70710678118654752f;
    float2 t0 = cadd(v[0], v[4]), t1 = csub(v[0], v[4]);
    float2 t2 = cadd(v[2], v[6]), t3 = csub(v[2], v[6]);
    float2 s0 = cadd(v[1], v[5]), s1 = csub(v[1], v[5]);
    float2 s2 = cadd(v[3], v[7]), s3 = csub(v[3], v[7]);
    float2 rt3 = rot90<INV>(t3), rs3 = rot90<INV>(s3);
    float2 E0 = cadd(t0, t2), E1 = cadd(t1, rt3), E2 = csub(t0, t2), E3 = csub(t1, rt3);
    float2 O0 = cadd(s0, s2), O1 = cadd(s1, rs3), O2 = csub(s0, s2), O3 = csub(s1, rs3);
    float2 rO1 = rot90<INV>(O1), rO2 = rot90<INV>(O2), rO3 = rot90<INV>(O3);
    // w8^1*z = R2*(z + rot90(z)); w8^3*z = R2*(rot90(z) - z)  (both directions)
    float2 a1 = make_float2(R2 * (O1.x + rO1.x), R2 * (O1.y + rO1.y));
    float2 a2 = rO2;
    float2 a3 = make_float2(R2 * (rO3.x - O3.x), R2 * (rO3.y - O3.y));
    v[0] = cadd(E0, O0); v[4] = csub(E0, O0);
    v[1] = cadd(E1, a1); v[5] = csub(E1, a1);
    v[2] = cadd(E2, a2); v[6] = csub(E2, a2);
    v[3] = cadd(E3, a3); v[7] = csub(E3, a3);
}

// Apply v[m] *= w1^m, m=1..7 (w1^0 = 1).
__device__ inline void twiddle8(float2 v[8], float2 w1) {
    float2 w2 = cmulf(w1, w1);
    float2 w3 = cmulf(w2, w1);
    float2 w4 = cmulf(w2, w2);
    float2 w5 = cmulf(w4, w1);
    float2 w6 = cmulf(w3, w3);
    float2 w7 = cmulf(w4, w3);
    v[1] = cmulf(v[1], w1); v[2] = cmulf(v[2], w2); v[3] = cmulf(v[3], w3);
    v[4] = cmulf(v[4], w4); v[5] = cmulf(v[5], w5); v[6] = cmulf(v[6], w6);
    v[7] = cmulf(v[7], w7);
}

// 512-point FFT fully owned by ONE 64-lane wave: radix-8 x 3 stages,
// 8 elements per lane in registers, 2 LDS round-trips, ZERO barriers.
// Stockham DIF (generalization of the verified radix-4 form):
//   stage s in {1,8,64}: p = lane/s, q = lane%s, A_j = a[lane + 64j],
//   b[q + 8sp + s*m] = w1^m * DFT8_m(A),  w1 = exp(-+2*pi*i*p*s/512).
// Stage 2 has p=0 -> twiddle-free; output v[m] = X[lane + 64m] natural order.
template <bool INV>
__device__ inline void fft512_wave(float2 v[8], float2* bufA, float2* bufB, int lane) {
    const float sg = INV ? (6.2831853071795865f / 512.0f)
                         : (-6.2831853071795865f / 512.0f);
    // stage 0: s=1, p=lane
    dft8<INV>(v);
    {
        float ang = sg * (float)lane;
        float2 w1;
        sincosf(ang, &w1.y, &w1.x);
        twiddle8(v, w1);
    }
#pragma unroll
    for (int m = 0; m < 8; ++m) bufA[FI(8 * lane + m)] = v[m];
    wave_fence();
#pragma unroll
    for (int j = 0; j < 8; ++j) v[j] = bufA[FI(lane + 64 * j)];
    // stage 1: s=8, p=lane>>3  (p*s = lane & 56)
    dft8<INV>(v);
    {
        float ang = sg * (float)(lane & 56);
        float2 w1;
        sincosf(ang, &w1.y, &w1.x);
        twiddle8(v, w1);
    }
    {
        int ob = (lane & 7) + ((lane >> 3) << 6);
#pragma unroll
        for (int m = 0; m < 8; ++m) bufB[FI(ob + 8 * m)] = v[m];
    }
    wave_fence();
#pragma unroll
    for (int j = 0; j < 8; ++j) v[j] = bufB[FI(lane + 64 * j)];
    // stage 2: s=64, p=0 -> no twiddle
    dft8<INV>(v);
}

// K1: real FFT of rows of x. 4 rows per block, ONE WAVE PER ROW.
__global__ __launch_bounds__(256) void k_row_rfft(const float* __restrict__ x,
                                                  float2* __restrict__ G) {
    __shared__ float2 lds[4][2][544];
    int lane = threadIdx.x & 63;
    int w = threadIdx.x >> 6;
    int row = blockIdx.x * 4 + w;  // nc*512 + h, 65536 rows
    const float* xr = x + (size_t)row * 512;
    float2 v[8];
#pragma unroll
    for (int j = 0; j < 8; ++j) v[j] = make_float2(xr[lane + 64 * j], 0.0f);
    fft512_wave<false>(v, lds[w][0], lds[w][1], lane);
    float2* g = G + (size_t)row * 257;
#pragma unroll
    for (int m = 0; m < 4; ++m) g[lane + 64 * m] = v[m];
    if (lane == 0) g[256] = v[4];
}

// K2: FFT along h, one wave per (nc, v) column. XCD-chunk swizzled so
// v-neighbor blocks (sharing G's 2056-B rows in L2) co-locate per XCD.
__global__ __launch_bounds__(256) void k_col_fft(const float2* __restrict__ G,
                                                 float2* __restrict__ XT) {
    __shared__ float2 lds[4][2][544];
    int lane = threadIdx.x & 63;
    int w = threadIdx.x >> 6;
    int l = xcd_remap(blockIdx.x, 1040);  // grid = 8320
    int nc = l / 65;
    int v = (l % 65) * 4 + w;
    if (v >= 257) return;  // no barriers in kernel -> uniform wave exit safe
    float2 vv[8];
#pragma unroll
    for (int j = 0; j < 8; ++j)
        vv[j] = G[((size_t)nc * 512 + lane + 64 * j) * 257 + v];
    fft512_wave<false>(vv, lds[w][0], lds[w][1], lane);
    float2* dst = XT + ((size_t)nc * 257 + v) * 512;
#pragma unroll
    for (int m = 0; m < 8; ++m) dst[lane + 64 * m] = vv[m];
}

// K3: complex 3x3 conv, 16->16 channels, zero padding, on the half-spectrum.
// V-PAIR TILING (round-6 winner, unchanged): block = 64-u x 2-v tile;
// o wave-uniform (scalar weight loads), lane = u.
__global__ __launch_bounds__(256, 4) void k_conv(const float2* __restrict__ XT,
                                                 float2* __restrict__ YT,
                                                 const float* __restrict__ wr,
                                                 const float* __restrict__ wi,
                                                 const float* __restrict__ br,
                                                 const float* __restrict__ bi) {
    __shared__ float2 Xs[16 * 4 * 66];  // [c][dvr][uu]; vg = v0-1+dvr
    int tid = threadIdx.x;
    int bid = blockIdx.x;
    int ut = bid & 7;
    int rest = bid >> 3;
    int vt = rest % 129;
    int n = rest / 129;
    int u0 = ut * 64;
    int v0 = vt * 2;

    for (int l = tid; l < 4224; l += 256) {
        int c = l / 264;
        int rem = l - c * 264;
        int dvr = rem / 66;
        int uu = rem - dvr * 66;
        int vg = v0 - 1 + dvr;
        int ug = u0 - 1 + uu;
        float2 val = make_float2(0.0f, 0.0f);
        if (vg >= 0 && vg < 257 && ug >= 0 && ug < 512)
            val = XT[(((size_t)n * 16 + c) * 257 + vg) * 512 + ug];
        Xs[l] = val;
    }
    __syncthreads();

    int lane = tid & 63;
    int wv = __builtin_amdgcn_readfirstlane(tid >> 6);
    int o0 = wv * 4;

    float2 acc[2][4];
#pragma unroll
    for (int oo = 0; oo < 4; ++oo) {
        float2 bv = make_float2(br[o0 + oo], bi[o0 + oo]);
        acc[0][oo] = bv;
        acc[1][oo] = bv;
    }

    for (int c = 0; c < 16; ++c) {
        float2 xv[4][3];
#pragma unroll
        for (int dvr = 0; dvr < 4; ++dvr) {
            const float2* row = &Xs[(c * 4 + dvr) * 66];
            xv[dvr][0] = row[lane];
            xv[dvr][1] = row[lane + 1];
            xv[dvr][2] = row[lane + 2];
        }
#pragma unroll
        for (int oo = 0; oo < 4; ++oo) {
            const float* wrp = wr + ((size_t)(c * 16 + o0 + oo)) * 9;
            const float* wip = wi + ((size_t)(c * 16 + o0 + oo)) * 9;
            float wre[9], wim[9];
#pragma unroll
            for (int t = 0; t < 9; ++t) { wre[t] = wrp[t]; wim[t] = wip[t]; }
#pragma unroll
            for (int kw = 0; kw < 3; ++kw) {
#pragma unroll
                for (int kh = 0; kh < 3; ++kh) {
                    int t = kh * 3 + kw;
                    int xj = 2 - kh;
                    float2 w = make_float2(wre[t], wim[t]);
                    cmac(acc[0][oo], w, xv[2 - kw][xj]);
                    cmac(acc[1][oo], w, xv[3 - kw][xj]);
                }
            }
        }
    }

#pragma unroll
    for (int oo = 0; oo < 4; ++oo) {
#pragma unroll
        for (int vv = 0; vv < 2; ++vv) {
            int v = v0 + vv;
            if (v < 257)
                YT[(((size_t)n * 16 + o0 + oo) * 257 + v) * 512 + u0 + lane] =
                    acc[vv][oo];
        }
    }
}

// K4: inverse FFT along u (scale 1/512), one wave per (no, v) column.
// Reads/writes coalesced.
__global__ __launch_bounds__(256) void k_col_ifft(const float2* __restrict__ YT,
                                                  float2* __restrict__ ZT) {
    __shared__ float2 lds[4][2][544];
    int lane = threadIdx.x & 63;
    int w = threadIdx.x >> 6;
    int no = blockIdx.x / 65;  // grid = 8320
    int v = (blockIdx.x % 65) * 4 + w;
    if (v >= 257) return;
    const float2* src = YT + ((size_t)no * 257 + v) * 512;
    float2 vv[8];
#pragma unroll
    for (int j = 0; j < 8; ++j) vv[j] = src[lane + 64 * j];
    fft512_wave<true>(vv, lds[w][0], lds[w][1], lane);
    const float sc = 1.0f / 512.0f;
    float2* dst = ZT + ((size_t)no * 257 + v) * 512;
#pragma unroll
    for (int m = 0; m < 8; ++m)
        dst[lane + 64 * m] = make_float2(vv[m].x * sc, vv[m].y * sc);
}

// K5: irfft along v, one wave per (no, h) row. Conjugate extension done
// per-lane at load (no LDS staging). XCD-chunk swizzled.
__global__ __launch_bounds__(256) void k_row_irfft(const float2* __restrict__ ZT,
                                                   float* __restrict__ out) {
    __shared__ float2 lds[4][2][544];
    int lane = threadIdx.x & 63;
    int w = threadIdx.x >> 6;
    int l = xcd_remap(blockIdx.x, 2048);  // grid = 16384
    int no = l >> 7;
    int h = (l & 127) * 4 + w;
    float2 v[8];
#pragma unroll
    for (int j = 0; j < 8; ++j) {
        int i = lane + 64 * j;
        float2 val;
        if (i <= 256) {
            val = ZT[((size_t)no * 257 + i) * 512 + h];
            if (i == 0 || i == 256) val.y = 0.0f;  // DC/Nyquist imag ignored
        } else {
            val = ZT[((size_t)no * 257 + (512 - i)) * 512 + h];
            val.y = -val.y;  // conjugate symmetry
        }
        v[j] = val;
    }
    fft512_wave<true>(v, lds[w][0], lds[w][1], lane);
    const float sc = 1.0f / 512.0f;
    float* dst = out + ((size_t)no * 512 + h) * 512;
#pragma unroll
    for (int m = 0; m < 8; ++m) dst[lane + 64 * m] = v[m].x * sc;
}

extern "C" void kernel_launch(void* const* d_in, const int* in_sizes, int n_in,
                              void* d_out, int out_size, void* d_ws, size_t ws_size,
                              hipStream_t stream) {
    const float* x  = (const float*)d_in[0];
    const float* wr = (const float*)d_in[1];
    const float* wi = (const float*)d_in[2];
    const float* br = (const float*)d_in[3];
    const float* bi = (const float*)d_in[4];
    float* out = (float*)d_out;

    const size_t bufElems = (size_t)128 * 257 * 512;  // complex elements
    float2* A = (float2*)d_ws;
    float2* B = A + bufElems;

    k_row_rfft<<<16384, 256, 0, stream>>>(x, A);                     // x -> G (A)
    k_col_fft<<<128 * 65, 256, 0, stream>>>(A, B);                   // G -> XT (B)
    k_conv<<<8 * 129 * 8, 256, 0, stream>>>(B, A, wr, wi, br, bi);   // XT -> YT (A)
    k_col_ifft<<<128 * 65, 256, 0, stream>>>(A, B);                  // YT -> ZT (B)
    k_row_irfft<<<16384, 256, 0, stream>>>(B, out);                  // ZT -> out
}

// Round 8
// 637.556 us; speedup vs baseline: 1.0941x; 1.0941x over previous
//
#include <hip/hip_runtime.h>
#include <math.h>

#define PI_F 3.14159265358979323846f

// LDS padding: +1 complex slot every 16.
#define FI(i) ((i) + ((i) >> 4))
#define CSTRIDE 544  // block-FFT per-column stride: 512 + 32
#define TSTRIDE 546  // tile row stride (1092 words; %32==4 -> <=2-way banks)

__device__ inline float2 cmulf(float2 a, float2 b) {
    return make_float2(a.x * b.x - a.y * b.y, a.x * b.y + a.y * b.x);
}
__device__ inline float2 cadd(float2 a, float2 b) { return make_float2(a.x + b.x, a.y + b.y); }
__device__ inline float2 csub(float2 a, float2 b) { return make_float2(a.x - b.x, a.y - b.y); }

__device__ inline void cmac(float2& a, float2 w, float2 v) {
    a.x = fmaf(w.x, v.x, a.x);
    a.x = fmaf(-w.y, v.y, a.x);
    a.y = fmaf(w.x, v.y, a.y);
    a.y = fmaf(w.y, v.x, a.y);
}

// Bijective chunked XCD remap (grid % 8 == 0).
__device__ inline int xcd_remap(int bid, int q) {
    return (bid & 7) * q + (bid >> 3);
}

__device__ inline void build_tbl128(float2* tbl, int tid) {
    if (tid < 128) {
        float ang = -2.0f * PI_F * (float)tid * (1.0f / 512.0f);
        tbl[tid] = make_float2(cosf(ang), sinf(ang));
    }
}

// ---------- block radix-4 Stockham (round-6 verified; K1/K4) ----------
template <int NCOLS>
__device__ inline float2* fft512_r4(float2* a, float2* b, const float2* tbl, int tid, bool inv) {
    const int bf = tid & 127;
    const int cp = tid >> 7;
#pragma unroll
    for (int st = 0; st < 4; ++st) {
        const int slog = 2 * st;
        const int s = 1 << slog;
        const int p = bf >> slog;
        const int q = bf & (s - 1);
        float2 w1 = tbl[p << slog];
        if (inv) w1.y = -w1.y;
        const float2 w2 = cmulf(w1, w1);
        const float2 w3 = cmulf(w2, w1);
        const int i0 = bf;
        const int ob = q + (p << (slog + 2));
#pragma unroll
        for (int t = 0; t < NCOLS / 2; ++t) {
            const int cc = cp + 2 * t;
            const float2* ac = a + cc * CSTRIDE;
            float2* bc = b + cc * CSTRIDE;
            float2 A = ac[FI(i0)];
            float2 B = ac[FI(i0 + 128)];
            float2 C = ac[FI(i0 + 256)];
            float2 D = ac[FI(i0 + 384)];
            float2 apc = cadd(A, C), amc = csub(A, C);
            float2 bpd = cadd(B, D), bmd = csub(B, D);
            float2 jb = make_float2(-bmd.y, bmd.x);
            if (inv) { jb.x = -jb.x; jb.y = -jb.y; }
            bc[FI(ob)]           = cadd(apc, bpd);
            bc[FI(ob + s)]       = cmulf(csub(amc, jb), w1);
            bc[FI(ob + 2 * s)]   = cmulf(csub(apc, bpd), w2);
            bc[FI(ob + 3 * s)]   = cmulf(cadd(amc, jb), w3);
        }
        __syncthreads();
        float2* tmp = a; a = b; b = tmp;
    }
    {
#pragma unroll
        for (int cc = 0; cc < NCOLS; ++cc) {
            const float2* ac = a + cc * CSTRIDE;
            float2* bc = b + cc * CSTRIDE;
            float2 A = ac[FI(tid)];
            float2 B = ac[FI(tid + 256)];
            bc[FI(tid)]       = cadd(A, B);
            bc[FI(tid + 256)] = csub(A, B);
        }
        __syncthreads();
        float2* tmp = a; a = b; b = tmp;
    }
    return a;
}

// ---------- wave radix-8 primitives (round-7 verified; K2/K5) ----------
__device__ inline void wave_fence() {
    asm volatile("s_waitcnt lgkmcnt(0)" ::: "memory");
    __builtin_amdgcn_sched_barrier(0);
}

template <bool INV>
__device__ inline float2 rot90(float2 z) {
    return INV ? make_float2(-z.y, z.x) : make_float2(z.y, -z.x);
}

template <bool INV>
__device__ inline void dft8(float2 v[8]) {
    const float R2 = 0.70710678118654752f;
    float2 t0 = cadd(v[0], v[4]), t1 = csub(v[0], v[4]);
    float2 t2 = cadd(v[2], v[6]), t3 = csub(v[2], v[6]);
    float2 s0 = cadd(v[1], v[5]), s1 = csub(v[1], v[5]);
    float2 s2 = cadd(v[3], v[7]), s3 = csub(v[3], v[7]);
    float2 rt3 = rot90<INV>(t3), rs3 = rot90<INV>(s3);
    float2 E0 = cadd(t0, t2), E1 = cadd(t1, rt3), E2 = csub(t0, t2), E3 = csub(t1, rt3);
    float2 O0 = cadd(s0, s2), O1 = cadd(s1, rs3), O2 = csub(s0, s2), O3 = csub(s1, rs3);
    float2 rO1 = rot90<INV>(O1), rO2 = rot90<INV>(O2), rO3 = rot90<INV>(O3);
    float2 a1 = make_float2(R2 * (O1.x + rO1.x), R2 * (O1.y + rO1.y));
    float2 a2 = rO2;
    float2 a3 = make_float2(R2 * (rO3.x - O3.x), R2 * (rO3.y - O3.y));
    v[0] = cadd(E0, O0); v[4] = csub(E0, O0);
    v[1] = cadd(E1, a1); v[5] = csub(E1, a1);
    v[2] = cadd(E2, a2); v[6] = csub(E2, a2);
    v[3] = cadd(E3, a3); v[7] = csub(E3, a3);
}

__device__ inline void twiddle8(float2 v[8], float2 w1) {
    float2 w2 = cmulf(w1, w1);
    float2 w3 = cmulf(w2, w1);
    float2 w4 = cmulf(w2, w2);
    float2 w5 = cmulf(w4, w1);
    float2 w6 = cmulf(w3, w3);
    float2 w7 = cmulf(w4, w3);
    v[1] = cmulf(v[1], w1); v[2] = cmulf(v[2], w2); v[3] = cmulf(v[3], w3);
    v[4] = cmulf(v[4], w4); v[5] = cmulf(v[5], w5); v[6] = cmulf(v[6], w6);
    v[7] = cmulf(v[7], w7);
}

// 512-pt radix-8^3 Stockham, one wave, IN-PLACE in R (FI-indexed row).
// v[] holds input x[lane+64j] on entry, X[lane+64m] natural order on exit.
// In-place safety: per stage, all 8 reads complete (register dependency via
// dft8) before any write issues; same-wave DS ops execute in order.
template <bool INV>
__device__ inline void fft512_wave_ip(float2 v[8], float2* R, int lane) {
    const float sg = INV ? (6.2831853071795865f / 512.0f)
                         : (-6.2831853071795865f / 512.0f);
    float2 w1;
    __sincosf(sg * (float)lane, &w1.y, &w1.x);
    // stage 0: s=1, p=lane
    dft8<INV>(v);
    twiddle8(v, w1);
#pragma unroll
    for (int m = 0; m < 8; ++m) R[FI(8 * lane + m)] = v[m];
    wave_fence();
#pragma unroll
    for (int j = 0; j < 8; ++j) v[j] = R[FI(lane + 64 * j)];
    // stage 1: s=8, p=lane>>3; w1' = w1 of lane (lane & 56) -> shuffle
    float2 w1b;
    w1b.x = __shfl(w1.x, lane & 56);
    w1b.y = __shfl(w1.y, lane & 56);
    dft8<INV>(v);
    twiddle8(v, w1b);
    {
        int ob = (lane & 7) + ((lane >> 3) << 6);
#pragma unroll
        for (int m = 0; m < 8; ++m) R[FI(ob + 8 * m)] = v[m];
    }
    wave_fence();
#pragma unroll
    for (int j = 0; j < 8; ++j) v[j] = R[FI(lane + 64 * j)];
    // stage 2: s=64, p=0 -> twiddle-free
    dft8<INV>(v);
}

// K1: real FFT of rows of x, 4 rows per block (round-6 form).
__global__ __launch_bounds__(256) void k_row_rfft(const float* __restrict__ x,
                                                  float2* __restrict__ G) {
    __shared__ float2 b0[4 * CSTRIDE], b1[4 * CSTRIDE], tbl[128];
    int tid = threadIdx.x;
    int nc = blockIdx.x >> 7;
    int h0 = (blockIdx.x & 127) * 4;
    build_tbl128(tbl, tid);
    const float4* xr = (const float4*)(x + ((size_t)nc * 512 + h0) * 512);
#pragma unroll
    for (int j = 0; j < 2; ++j) {
        int t4 = tid + 256 * j;
        float4 v = xr[t4];
        int e = t4 * 4;
        int k = e >> 9, i = e & 511;
        float2* dst = b0 + k * CSTRIDE + FI(i);
        dst[0] = make_float2(v.x, 0.0f);
        dst[1] = make_float2(v.y, 0.0f);
        dst[2] = make_float2(v.z, 0.0f);
        dst[3] = make_float2(v.w, 0.0f);
    }
    __syncthreads();
    float2* res = fft512_r4<4>(b0, b1, tbl, tid, false);
#pragma unroll
    for (int k = 0; k < 4; ++k) {
        float2* g = G + ((size_t)(nc * 512 + h0 + k)) * 257;
        g[tid] = res[k * CSTRIDE + FI(tid)];
        if (tid == 0) g[256] = res[k * CSTRIDE + FI(256)];
    }
}

// K2: FFT along h for 16 v-columns per block. COALESCED tile load (16
// consecutive v = 128-B lines), LDS transpose, one wave per column doing
// the in-place radix-8 FFT in its own tile row. One barrier total.
__global__ __launch_bounds__(1024) void k_col_fft(const float2* __restrict__ G,
                                                  float2* __restrict__ XT) {
    __shared__ float2 tile[16][TSTRIDE];
    int tid = threadIdx.x;
    int l = xcd_remap(blockIdx.x, 272);  // grid = 2176 = 128 nc * 17 vt
    int nc = l / 17;
    int v0 = (l % 17) * 16;
#pragma unroll
    for (int j = 0; j < 8; ++j) {
        int e = tid + 1024 * j;   // over 512*16
        int dv = e & 15, h = e >> 4;
        int v = v0 + dv;
        float2 val = make_float2(0.0f, 0.0f);
        if (v < 257) val = G[((size_t)nc * 512 + h) * 257 + v];
        tile[dv][FI(h)] = val;
    }
    __syncthreads();
    int lane = tid & 63, w = tid >> 6;
    float2* R = tile[w];
    float2 vv[8];
#pragma unroll
    for (int j = 0; j < 8; ++j) vv[j] = R[FI(lane + 64 * j)];
    fft512_wave_ip<false>(vv, R, lane);
    int v = v0 + w;
    if (v < 257) {
        float2* dst = XT + ((size_t)nc * 257 + v) * 512;
#pragma unroll
        for (int m = 0; m < 8; ++m) dst[lane + 64 * m] = vv[m];
    }
}

// K3: complex 3x3 conv (round-6 v-pair form, unchanged).
__global__ __launch_bounds__(256, 4) void k_conv(const float2* __restrict__ XT,
                                                 float2* __restrict__ YT,
                                                 const float* __restrict__ wr,
                                                 const float* __restrict__ wi,
                                                 const float* __restrict__ br,
                                                 const float* __restrict__ bi) {
    __shared__ float2 Xs[16 * 4 * 66];
    int tid = threadIdx.x;
    int bid = blockIdx.x;
    int ut = bid & 7;
    int rest = bid >> 3;
    int vt = rest % 129;
    int n = rest / 129;
    int u0 = ut * 64;
    int v0 = vt * 2;

    for (int l = tid; l < 4224; l += 256) {
        int c = l / 264;
        int rem = l - c * 264;
        int dvr = rem / 66;
        int uu = rem - dvr * 66;
        int vg = v0 - 1 + dvr;
        int ug = u0 - 1 + uu;
        float2 val = make_float2(0.0f, 0.0f);
        if (vg >= 0 && vg < 257 && ug >= 0 && ug < 512)
            val = XT[(((size_t)n * 16 + c) * 257 + vg) * 512 + ug];
        Xs[l] = val;
    }
    __syncthreads();

    int lane = tid & 63;
    int wv = __builtin_amdgcn_readfirstlane(tid >> 6);
    int o0 = wv * 4;

    float2 acc[2][4];
#pragma unroll
    for (int oo = 0; oo < 4; ++oo) {
        float2 bv = make_float2(br[o0 + oo], bi[o0 + oo]);
        acc[0][oo] = bv;
        acc[1][oo] = bv;
    }

    for (int c = 0; c < 16; ++c) {
        float2 xv[4][3];
#pragma unroll
        for (int dvr = 0; dvr < 4; ++dvr) {
            const float2* row = &Xs[(c * 4 + dvr) * 66];
            xv[dvr][0] = row[lane];
            xv[dvr][1] = row[lane + 1];
            xv[dvr][2] = row[lane + 2];
        }
#pragma unroll
        for (int oo = 0; oo < 4; ++oo) {
            const float* wrp = wr + ((size_t)(c * 16 + o0 + oo)) * 9;
            const float* wip = wi + ((size_t)(c * 16 + o0 + oo)) * 9;
            float wre[9], wim[9];
#pragma unroll
            for (int t = 0; t < 9; ++t) { wre[t] = wrp[t]; wim[t] = wip[t]; }
#pragma unroll
            for (int kw = 0; kw < 3; ++kw) {
#pragma unroll
                for (int kh = 0; kh < 3; ++kh) {
                    int t = kh * 3 + kw;
                    int xj = 2 - kh;
                    float2 w = make_float2(wre[t], wim[t]);
                    cmac(acc[0][oo], w, xv[2 - kw][xj]);
                    cmac(acc[1][oo], w, xv[3 - kw][xj]);
                }
            }
        }
    }

#pragma unroll
    for (int oo = 0; oo < 4; ++oo) {
#pragma unroll
        for (int vv = 0; vv < 2; ++vv) {
            int v = v0 + vv;
            if (v < 257)
                YT[(((size_t)n * 16 + o0 + oo) * 257 + v) * 512 + u0 + lane] =
                    acc[vv][oo];
        }
    }
}

// K4: inverse FFT along u (scale 1/512) for 4 columns (round-6 form).
__global__ __launch_bounds__(256) void k_col_ifft(const float2* __restrict__ YT,
                                                  float2* __restrict__ ZT) {
    __shared__ float2 b0[4 * CSTRIDE], b1[4 * CSTRIDE], tbl[128];
    int tid = threadIdx.x;
    int no = blockIdx.x / 65;
    int v0 = (blockIdx.x % 65) * 4;
    build_tbl128(tbl, tid);
#pragma unroll
    for (int k = 0; k < 4; ++k) {
        int v = v0 + k;
        const float2* src = YT + ((size_t)no * 257 + (v < 257 ? v : 256)) * 512;
        b0[k * CSTRIDE + FI(tid)]       = src[tid];
        b0[k * CSTRIDE + FI(tid + 256)] = src[tid + 256];
    }
    __syncthreads();
    float2* res = fft512_r4<4>(b0, b1, tbl, tid, true);
    const float sc = 1.0f / 512.0f;
#pragma unroll
    for (int k = 0; k < 4; ++k) {
        int v = v0 + k;
        if (v < 257) {
            float2* dst = ZT + ((size_t)no * 257 + v) * 512;
            float2 r0 = res[k * CSTRIDE + FI(tid)];
            float2 r1 = res[k * CSTRIDE + FI(tid + 256)];
            dst[tid]       = make_float2(r0.x * sc, r0.y * sc);
            dst[tid + 256] = make_float2(r1.x * sc, r1.y * sc);
        }
    }
}

// K5: irfft along v for 16 h-rows per block. COALESCED tile load (16
// consecutive h = one 128-B line per vv-row), conjugate extension at
// register fill, in-place wave radix-8 IFFT, coalesced row stores.
__global__ __launch_bounds__(1024) void k_row_irfft(const float2* __restrict__ ZT,
                                                    float* __restrict__ out) {
    __shared__ float2 tile[16][TSTRIDE];
    int tid = threadIdx.x;
    int no = blockIdx.x >> 5;        // grid = 128 * 32
    int h0 = (blockIdx.x & 31) * 16;
#pragma unroll
    for (int j = 0; j < 5; ++j) {
        int e = tid + 1024 * j;      // over 257*16 = 4112
        if (e < 4112) {
            int dh = e & 15, vv = e >> 4;
            tile[dh][FI(vv)] = ZT[((size_t)no * 257 + vv) * 512 + h0 + dh];
        }
    }
    __syncthreads();
    int lane = tid & 63, w = tid >> 6;
    float2* R = tile[w];
    float2 v[8];
#pragma unroll
    for (int j = 0; j < 8; ++j) {
        int i = lane + 64 * j;
        float2 val;
        if (i <= 256) {
            val = R[FI(i)];
            if (i == 0 || i == 256) val.y = 0.0f;  // DC/Nyquist imag ignored
        } else {
            val = R[FI(512 - i)];
            val.y = -val.y;                        // conjugate symmetry
        }
        v[j] = val;
    }
    fft512_wave_ip<true>(v, R, lane);
    const float sc = 1.0f / 512.0f;
    float* dst = out + ((size_t)no * 512 + h0 + w) * 512;
#pragma unroll
    for (int m = 0; m < 8; ++m) dst[lane + 64 * m] = v[m].x * sc;
}

extern "C" void kernel_launch(void* const* d_in, const int* in_sizes, int n_in,
                              void* d_out, int out_size, void* d_ws, size_t ws_size,
                              hipStream_t stream) {
    const float* x  = (const float*)d_in[0];
    const float* wr = (const float*)d_in[1];
    const float* wi = (const float*)d_in[2];
    const float* br = (const float*)d_in[3];
    const float* bi = (const float*)d_in[4];
    float* out = (float*)d_out;

    const size_t bufElems = (size_t)128 * 257 * 512;  // complex elements
    float2* A = (float2*)d_ws;
    float2* B = A + bufElems;

    k_row_rfft<<<128 * 128, 256, 0, stream>>>(x, A);                 // x -> G (A)
    k_col_fft<<<128 * 17, 1024, 0, stream>>>(A, B);                  // G -> XT (B)
    k_conv<<<8 * 129 * 8, 256, 0, stream>>>(B, A, wr, wi, br, bi);   // XT -> YT (A)
    k_col_ifft<<<128 * 65, 256, 0, stream>>>(A, B);                  // YT -> ZT (B)
    k_row_irfft<<<128 * 32, 1024, 0, stream>>>(B, out);              // ZT -> out
}

// Round 9
// 615.860 us; speedup vs baseline: 1.1326x; 1.0352x over previous
//
#include <hip/hip_runtime.h>
#include <math.h>

#define PI_F 3.14159265358979323846f

// LDS padding: +1 complex slot every 16.
#define FI(i) ((i) + ((i) >> 4))
#define CSTRIDE 544  // block-FFT per-column stride: 512 + 32
#define TSTRIDE 546  // tile row stride (1092 words; %32==4 -> <=2-way banks)

__device__ inline float2 cmulf(float2 a, float2 b) {
    return make_float2(a.x * b.x - a.y * b.y, a.x * b.y + a.y * b.x);
}
__device__ inline float2 cadd(float2 a, float2 b) { return make_float2(a.x + b.x, a.y + b.y); }
__device__ inline float2 csub(float2 a, float2 b) { return make_float2(a.x - b.x, a.y - b.y); }

__device__ inline void cmac(float2& a, float2 w, float2 v) {
    a.x = fmaf(w.x, v.x, a.x);
    a.x = fmaf(-w.y, v.y, a.x);
    a.y = fmaf(w.x, v.y, a.y);
    a.y = fmaf(w.y, v.x, a.y);
}

// Bijective chunked XCD remap (grid % 8 == 0).
__device__ inline int xcd_remap(int bid, int q) {
    return (bid & 7) * q + (bid >> 3);
}

__device__ inline void build_tbl128(float2* tbl, int tid) {
    if (tid < 128) {
        float ang = -2.0f * PI_F * (float)tid * (1.0f / 512.0f);
        tbl[tid] = make_float2(cosf(ang), sinf(ang));
    }
}

// ---------- block radix-4 Stockham (K4) ----------
template <int NCOLS>
__device__ inline float2* fft512_r4(float2* a, float2* b, const float2* tbl, int tid, bool inv) {
    const int bf = tid & 127;
    const int cp = tid >> 7;
#pragma unroll
    for (int st = 0; st < 4; ++st) {
        const int slog = 2 * st;
        const int s = 1 << slog;
        const int p = bf >> slog;
        const int q = bf & (s - 1);
        float2 w1 = tbl[p << slog];
        if (inv) w1.y = -w1.y;
        const float2 w2 = cmulf(w1, w1);
        const float2 w3 = cmulf(w2, w1);
        const int i0 = bf;
        const int ob = q + (p << (slog + 2));
#pragma unroll
        for (int t = 0; t < NCOLS / 2; ++t) {
            const int cc = cp + 2 * t;
            const float2* ac = a + cc * CSTRIDE;
            float2* bc = b + cc * CSTRIDE;
            float2 A = ac[FI(i0)];
            float2 B = ac[FI(i0 + 128)];
            float2 C = ac[FI(i0 + 256)];
            float2 D = ac[FI(i0 + 384)];
            float2 apc = cadd(A, C), amc = csub(A, C);
            float2 bpd = cadd(B, D), bmd = csub(B, D);
            float2 jb = make_float2(-bmd.y, bmd.x);
            if (inv) { jb.x = -jb.x; jb.y = -jb.y; }
            bc[FI(ob)]           = cadd(apc, bpd);
            bc[FI(ob + s)]       = cmulf(csub(amc, jb), w1);
            bc[FI(ob + 2 * s)]   = cmulf(csub(apc, bpd), w2);
            bc[FI(ob + 3 * s)]   = cmulf(cadd(amc, jb), w3);
        }
        __syncthreads();
        float2* tmp = a; a = b; b = tmp;
    }
    {
#pragma unroll
        for (int cc = 0; cc < NCOLS; ++cc) {
            const float2* ac = a + cc * CSTRIDE;
            float2* bc = b + cc * CSTRIDE;
            float2 A = ac[FI(tid)];
            float2 B = ac[FI(tid + 256)];
            bc[FI(tid)]       = cadd(A, B);
            bc[FI(tid + 256)] = csub(A, B);
        }
        __syncthreads();
        float2* tmp = a; a = b; b = tmp;
    }
    return a;
}

// ---------- wave radix-8 primitives (K1/K2/K5) ----------
__device__ inline void wave_fence() {
    asm volatile("s_waitcnt lgkmcnt(0)" ::: "memory");
    __builtin_amdgcn_sched_barrier(0);
}

template <bool INV>
__device__ inline float2 rot90(float2 z) {
    return INV ? make_float2(-z.y, z.x) : make_float2(z.y, -z.x);
}

template <bool INV>
__device__ inline void dft8(float2 v[8]) {
    const float R2 = 0.70710678118654752f;
    float2 t0 = cadd(v[0], v[4]), t1 = csub(v[0], v[4]);
    float2 t2 = cadd(v[2], v[6]), t3 = csub(v[2], v[6]);
    float2 s0 = cadd(v[1], v[5]), s1 = csub(v[1], v[5]);
    float2 s2 = cadd(v[3], v[7]), s3 = csub(v[3], v[7]);
    float2 rt3 = rot90<INV>(t3), rs3 = rot90<INV>(s3);
    float2 E0 = cadd(t0, t2), E1 = cadd(t1, rt3), E2 = csub(t0, t2), E3 = csub(t1, rt3);
    float2 O0 = cadd(s0, s2), O1 = cadd(s1, rs3), O2 = csub(s0, s2), O3 = csub(s1, rs3);
    float2 rO1 = rot90<INV>(O1), rO2 = rot90<INV>(O2), rO3 = rot90<INV>(O3);
    float2 a1 = make_float2(R2 * (O1.x + rO1.x), R2 * (O1.y + rO1.y));
    float2 a2 = rO2;
    float2 a3 = make_float2(R2 * (rO3.x - O3.x), R2 * (rO3.y - O3.y));
    v[0] = cadd(E0, O0); v[4] = csub(E0, O0);
    v[1] = cadd(E1, a1); v[5] = csub(E1, a1);
    v[2] = cadd(E2, a2); v[6] = csub(E2, a2);
    v[3] = cadd(E3, a3); v[7] = csub(E3, a3);
}

__device__ inline void twiddle8(float2 v[8], float2 w1) {
    float2 w2 = cmulf(w1, w1);
    float2 w3 = cmulf(w2, w1);
    float2 w4 = cmulf(w2, w2);
    float2 w5 = cmulf(w4, w1);
    float2 w6 = cmulf(w3, w3);
    float2 w7 = cmulf(w4, w3);
    v[1] = cmulf(v[1], w1); v[2] = cmulf(v[2], w2); v[3] = cmulf(v[3], w3);
    v[4] = cmulf(v[4], w4); v[5] = cmulf(v[5], w5); v[6] = cmulf(v[6], w6);
    v[7] = cmulf(v[7], w7);
}

// 512-pt radix-8^3 Stockham, one wave, IN-PLACE in R (FI-indexed row).
// v[] = x[lane+64j] on entry, X[lane+64m] natural order on exit.
template <bool INV>
__device__ inline void fft512_wave_ip(float2 v[8], float2* R, int lane) {
    const float sg = INV ? (6.2831853071795865f / 512.0f)
                         : (-6.2831853071795865f / 512.0f);
    float2 w1;
    __sincosf(sg * (float)lane, &w1.y, &w1.x);
    dft8<INV>(v);
    twiddle8(v, w1);
#pragma unroll
    for (int m = 0; m < 8; ++m) R[FI(8 * lane + m)] = v[m];
    wave_fence();
#pragma unroll
    for (int j = 0; j < 8; ++j) v[j] = R[FI(lane + 64 * j)];
    float2 w1b;
    w1b.x = __shfl(w1.x, lane & 56);
    w1b.y = __shfl(w1.y, lane & 56);
    dft8<INV>(v);
    twiddle8(v, w1b);
    {
        int ob = (lane & 7) + ((lane >> 3) << 6);
#pragma unroll
        for (int m = 0; m < 8; ++m) R[FI(ob + 8 * m)] = v[m];
    }
    wave_fence();
#pragma unroll
    for (int j = 0; j < 8; ++j) v[j] = R[FI(lane + 64 * j)];
    dft8<INV>(v);
}

// K1: real FFT of rows via PAIR-PACKING: z = x_h + i*x_{h+1}, one complex
// FFT per row pair, conjugate-symmetry unpack. One wave per pair, zero
// barriers, all global I/O coalesced. 32768 FFTs (was 65536).
__global__ __launch_bounds__(256) void k_row_rfft(const float* __restrict__ x,
                                                  float2* __restrict__ G) {
    __shared__ float2 lds[4][544];
    int lane = threadIdx.x & 63;
    int w = threadIdx.x >> 6;
    int pair = blockIdx.x * 4 + w;  // 32768 pairs; rows 2*pair, 2*pair+1
    const float* x0 = x + (size_t)(2 * pair) * 512;
    const float* x1 = x0 + 512;
    float2 v[8];
#pragma unroll
    for (int j = 0; j < 8; ++j)
        v[j] = make_float2(x0[lane + 64 * j], x1[lane + 64 * j]);
    fft512_wave_ip<false>(v, lds[w], lane);
    // partner P[m] = Z[(512 - (lane+64m)) & 511]
    float2 P[5];
#pragma unroll
    for (int m = 0; m < 5; ++m) {
        int src = (64 - lane) & 63;
        float2 p;
        p.x = __shfl(v[7 - m].x, src);
        p.y = __shfl(v[7 - m].y, src);
        if (lane == 0) p = v[(8 - m) & 7];
        P[m] = p;
    }
    float2* g0 = G + (size_t)(2 * pair) * 257;
    float2* g1 = g0 + 257;
#pragma unroll
    for (int m = 0; m < 4; ++m) {
        int k = lane + 64 * m;  // 0..255
        float2 Z = v[m], Pc = P[m];
        float2 S = make_float2(0.5f * (Z.x + Pc.x), 0.5f * (Z.y - Pc.y));
        float2 D = make_float2(Z.x - Pc.x, Z.y + Pc.y);
        float2 T = make_float2(0.5f * D.y, -0.5f * D.x);  // -i*D/2
        g0[k] = S;
        g1[k] = T;
    }
    if (lane == 0) {  // k = 256 (Nyquist)
        float2 Z = v[4], Pc = P[4];
        g0[256] = make_float2(0.5f * (Z.x + Pc.x), 0.5f * (Z.y - Pc.y));
        float2 D = make_float2(Z.x - Pc.x, Z.y + Pc.y);
        g1[256] = make_float2(0.5f * D.y, -0.5f * D.x);
    }
}

// K2: FFT along h for 16 v-columns per block (round-8 form, unchanged).
__global__ __launch_bounds__(1024) void k_col_fft(const float2* __restrict__ G,
                                                  float2* __restrict__ XT) {
    __shared__ float2 tile[16][TSTRIDE];
    int tid = threadIdx.x;
    int l = xcd_remap(blockIdx.x, 272);  // grid = 2176 = 128 nc * 17 vt
    int nc = l / 17;
    int v0 = (l % 17) * 16;
#pragma unroll
    for (int j = 0; j < 8; ++j) {
        int e = tid + 1024 * j;
        int dv = e & 15, h = e >> 4;
        int v = v0 + dv;
        float2 val = make_float2(0.0f, 0.0f);
        if (v < 257) val = G[((size_t)nc * 512 + h) * 257 + v];
        tile[dv][FI(h)] = val;
    }
    __syncthreads();
    int lane = tid & 63, w = tid >> 6;
    float2* R = tile[w];
    float2 vv[8];
#pragma unroll
    for (int j = 0; j < 8; ++j) vv[j] = R[FI(lane + 64 * j)];
    fft512_wave_ip<false>(vv, R, lane);
    int v = v0 + w;
    if (v < 257) {
        float2* dst = XT + ((size_t)nc * 257 + v) * 512;
#pragma unroll
        for (int m = 0; m < 8; ++m) dst[lane + 64 * m] = vv[m];
    }
}

// K3: complex 3x3 conv (round-6 v-pair form, unchanged).
__global__ __launch_bounds__(256, 4) void k_conv(const float2* __restrict__ XT,
                                                 float2* __restrict__ YT,
                                                 const float* __restrict__ wr,
                                                 const float* __restrict__ wi,
                                                 const float* __restrict__ br,
                                                 const float* __restrict__ bi) {
    __shared__ float2 Xs[16 * 4 * 66];
    int tid = threadIdx.x;
    int bid = blockIdx.x;
    int ut = bid & 7;
    int rest = bid >> 3;
    int vt = rest % 129;
    int n = rest / 129;
    int u0 = ut * 64;
    int v0 = vt * 2;

    for (int l = tid; l < 4224; l += 256) {
        int c = l / 264;
        int rem = l - c * 264;
        int dvr = rem / 66;
        int uu = rem - dvr * 66;
        int vg = v0 - 1 + dvr;
        int ug = u0 - 1 + uu;
        float2 val = make_float2(0.0f, 0.0f);
        if (vg >= 0 && vg < 257 && ug >= 0 && ug < 512)
            val = XT[(((size_t)n * 16 + c) * 257 + vg) * 512 + ug];
        Xs[l] = val;
    }
    __syncthreads();

    int lane = tid & 63;
    int wv = __builtin_amdgcn_readfirstlane(tid >> 6);
    int o0 = wv * 4;

    float2 acc[2][4];
#pragma unroll
    for (int oo = 0; oo < 4; ++oo) {
        float2 bv = make_float2(br[o0 + oo], bi[o0 + oo]);
        acc[0][oo] = bv;
        acc[1][oo] = bv;
    }

    for (int c = 0; c < 16; ++c) {
        float2 xv[4][3];
#pragma unroll
        for (int dvr = 0; dvr < 4; ++dvr) {
            const float2* row = &Xs[(c * 4 + dvr) * 66];
            xv[dvr][0] = row[lane];
            xv[dvr][1] = row[lane + 1];
            xv[dvr][2] = row[lane + 2];
        }
#pragma unroll
        for (int oo = 0; oo < 4; ++oo) {
            const float* wrp = wr + ((size_t)(c * 16 + o0 + oo)) * 9;
            const float* wip = wi + ((size_t)(c * 16 + o0 + oo)) * 9;
            float wre[9], wim[9];
#pragma unroll
            for (int t = 0; t < 9; ++t) { wre[t] = wrp[t]; wim[t] = wip[t]; }
#pragma unroll
            for (int kw = 0; kw < 3; ++kw) {
#pragma unroll
                for (int kh = 0; kh < 3; ++kh) {
                    int t = kh * 3 + kw;
                    int xj = 2 - kh;
                    float2 w = make_float2(wre[t], wim[t]);
                    cmac(acc[0][oo], w, xv[2 - kw][xj]);
                    cmac(acc[1][oo], w, xv[3 - kw][xj]);
                }
            }
        }
    }

#pragma unroll
    for (int oo = 0; oo < 4; ++oo) {
#pragma unroll
        for (int vv = 0; vv < 2; ++vv) {
            int v = v0 + vv;
            if (v < 257)
                YT[(((size_t)n * 16 + o0 + oo) * 257 + v) * 512 + u0 + lane] =
                    acc[vv][oo];
        }
    }
}

// K4: inverse FFT along u (scale 1/512) for 4 columns (round-6 form).
__global__ __launch_bounds__(256) void k_col_ifft(const float2* __restrict__ YT,
                                                  float2* __restrict__ ZT) {
    __shared__ float2 b0[4 * CSTRIDE], b1[4 * CSTRIDE], tbl[128];
    int tid = threadIdx.x;
    int no = blockIdx.x / 65;
    int v0 = (blockIdx.x % 65) * 4;
    build_tbl128(tbl, tid);
#pragma unroll
    for (int k = 0; k < 4; ++k) {
        int v = v0 + k;
        const float2* src = YT + ((size_t)no * 257 + (v < 257 ? v : 256)) * 512;
        b0[k * CSTRIDE + FI(tid)]       = src[tid];
        b0[k * CSTRIDE + FI(tid + 256)] = src[tid + 256];
    }
    __syncthreads();
    float2* res = fft512_r4<4>(b0, b1, tbl, tid, true);
    const float sc = 1.0f / 512.0f;
#pragma unroll
    for (int k = 0; k < 4; ++k) {
        int v = v0 + k;
        if (v < 257) {
            float2* dst = ZT + ((size_t)no * 257 + v) * 512;
            float2 r0 = res[k * CSTRIDE + FI(tid)];
            float2 r1 = res[k * CSTRIDE + FI(tid + 256)];
            dst[tid]       = make_float2(r0.x * sc, r0.y * sc);
            dst[tid + 256] = make_float2(r1.x * sc, r1.y * sc);
        }
    }
}

// K5: irfft along v via PAIR-UNPACKING: W = Zh + i*Zh1 (conjugate-extended),
// one inverse complex FFT per h-pair; Re -> row h, Im -> row h+1.
// 16-row tile (8 waves, one pair each), coalesced tile load, FFT in-place
// in tile row 2w. 16384 FFTs (was 32768).
__global__ __launch_bounds__(512) void k_row_irfft(const float2* __restrict__ ZT,
                                                   float* __restrict__ out) {
    __shared__ float2 tile[16][TSTRIDE];
    int tid = threadIdx.x;
    int no = blockIdx.x >> 5;        // grid = 128 * 32
    int h0 = (blockIdx.x & 31) * 16;
#pragma unroll
    for (int j = 0; j < 9; ++j) {
        int e = tid + 512 * j;       // over 257*16 = 4112
        if (e < 4112) {
            int dh = e & 15, vv = e >> 4;
            tile[dh][FI(vv)] = ZT[((size_t)no * 257 + vv) * 512 + h0 + dh];
        }
    }
    __syncthreads();
    int lane = tid & 63, w = tid >> 6;  // w in [0,8): pair rows 2w, 2w+1
    float2* Ra = tile[2 * w];
    float2* Rb = tile[2 * w + 1];
    float2 v[8];
#pragma unroll
    for (int m = 0; m < 8; ++m) {
        int i = lane + 64 * m;
        float2 a, b, W;
        if (i <= 256) {
            a = Ra[FI(i)];
            b = Rb[FI(i)];
            if (i == 0 || i == 256) { a.y = 0.0f; b.y = 0.0f; }
            W = make_float2(a.x - b.y, a.y + b.x);        // Zh + i*Zh1
        } else {
            int ii = 512 - i;  // 1..255
            a = Ra[FI(ii)];
            b = Rb[FI(ii)];
            W = make_float2(a.x + b.y, -a.y + b.x);       // conj(Zh)+i*conj(Zh1)
        }
        v[m] = W;
    }
    fft512_wave_ip<true>(v, Ra, lane);
    const float sc = 1.0f / 512.0f;
    float* d0 = out + ((size_t)no * 512 + h0 + 2 * w) * 512;
    float* d1 = d0 + 512;
#pragma unroll
    for (int m = 0; m < 8; ++m) {
        d0[lane + 64 * m] = v[m].x * sc;
        d1[lane + 64 * m] = v[m].y * sc;
    }
}

extern "C" void kernel_launch(void* const* d_in, const int* in_sizes, int n_in,
                              void* d_out, int out_size, void* d_ws, size_t ws_size,
                              hipStream_t stream) {
    const float* x  = (const float*)d_in[0];
    const float* wr = (const float*)d_in[1];
    const float* wi = (const float*)d_in[2];
    const float* br = (const float*)d_in[3];
    const float* bi = (const float*)d_in[4];
    float* out = (float*)d_out;

    const size_t bufElems = (size_t)128 * 257 * 512;  // complex elements
    float2* A = (float2*)d_ws;
    float2* B = A + bufElems;

    k_row_rfft<<<8192, 256, 0, stream>>>(x, A);                      // x -> G (A)
    k_col_fft<<<128 * 17, 1024, 0, stream>>>(A, B);                  // G -> XT (B)
    k_conv<<<8 * 129 * 8, 256, 0, stream>>>(B, A, wr, wi, br, bi);   // XT -> YT (A)
    k_col_ifft<<<128 * 65, 256, 0, stream>>>(A, B);                  // YT -> ZT (B)
    k_row_irfft<<<128 * 32, 512, 0, stream>>>(B, out);               // ZT -> out
}

// Round 10
// 593.423 us; speedup vs baseline: 1.1754x; 1.0378x over previous
//
#include <hip/hip_runtime.h>
#include <math.h>

#define PI_F 3.14159265358979323846f

// LDS padding: +1 complex slot every 16.
#define FI(i) ((i) + ((i) >> 4))
#define TSTRIDE 546  // tile row stride (1092 words; %32==4 -> <=2-way banks)

__device__ inline float2 cmulf(float2 a, float2 b) {
    return make_float2(a.x * b.x - a.y * b.y, a.x * b.y + a.y * b.x);
}
__device__ inline float2 cadd(float2 a, float2 b) { return make_float2(a.x + b.x, a.y + b.y); }
__device__ inline float2 csub(float2 a, float2 b) { return make_float2(a.x - b.x, a.y - b.y); }

__device__ inline void cmac(float2& a, float2 w, float2 v) {
    a.x = fmaf(w.x, v.x, a.x);
    a.x = fmaf(-w.y, v.y, a.x);
    a.y = fmaf(w.x, v.y, a.y);
    a.y = fmaf(w.y, v.x, a.y);
}

// Bijective chunked XCD remap (grid % 8 == 0).
__device__ inline int xcd_remap(int bid, int q) {
    return (bid & 7) * q + (bid >> 3);
}

// ---------- wave radix-8 primitives (K1/K2/K4/K5) ----------
__device__ inline void wave_fence() {
    asm volatile("s_waitcnt lgkmcnt(0)" ::: "memory");
    __builtin_amdgcn_sched_barrier(0);
}

template <bool INV>
__device__ inline float2 rot90(float2 z) {
    return INV ? make_float2(-z.y, z.x) : make_float2(z.y, -z.x);
}

template <bool INV>
__device__ inline void dft8(float2 v[8]) {
    const float R2 = 0.70710678118654752f;
    float2 t0 = cadd(v[0], v[4]), t1 = csub(v[0], v[4]);
    float2 t2 = cadd(v[2], v[6]), t3 = csub(v[2], v[6]);
    float2 s0 = cadd(v[1], v[5]), s1 = csub(v[1], v[5]);
    float2 s2 = cadd(v[3], v[7]), s3 = csub(v[3], v[7]);
    float2 rt3 = rot90<INV>(t3), rs3 = rot90<INV>(s3);
    float2 E0 = cadd(t0, t2), E1 = cadd(t1, rt3), E2 = csub(t0, t2), E3 = csub(t1, rt3);
    float2 O0 = cadd(s0, s2), O1 = cadd(s1, rs3), O2 = csub(s0, s2), O3 = csub(s1, rs3);
    float2 rO1 = rot90<INV>(O1), rO2 = rot90<INV>(O2), rO3 = rot90<INV>(O3);
    float2 a1 = make_float2(R2 * (O1.x + rO1.x), R2 * (O1.y + rO1.y));
    float2 a2 = rO2;
    float2 a3 = make_float2(R2 * (rO3.x - O3.x), R2 * (rO3.y - O3.y));
    v[0] = cadd(E0, O0); v[4] = csub(E0, O0);
    v[1] = cadd(E1, a1); v[5] = csub(E1, a1);
    v[2] = cadd(E2, a2); v[6] = csub(E2, a2);
    v[3] = cadd(E3, a3); v[7] = csub(E3, a3);
}

__device__ inline void twiddle8(float2 v[8], float2 w1) {
    float2 w2 = cmulf(w1, w1);
    float2 w3 = cmulf(w2, w1);
    float2 w4 = cmulf(w2, w2);
    float2 w5 = cmulf(w4, w1);
    float2 w6 = cmulf(w3, w3);
    float2 w7 = cmulf(w4, w3);
    v[1] = cmulf(v[1], w1); v[2] = cmulf(v[2], w2); v[3] = cmulf(v[3], w3);
    v[4] = cmulf(v[4], w4); v[5] = cmulf(v[5], w5); v[6] = cmulf(v[6], w6);
    v[7] = cmulf(v[7], w7);
}

// 512-pt radix-8^3 Stockham, one wave, IN-PLACE in R (FI-indexed row).
// v[] = x[lane+64j] on entry, X[lane+64m] natural order on exit.
template <bool INV>
__device__ inline void fft512_wave_ip(float2 v[8], float2* R, int lane) {
    const float sg = INV ? (6.2831853071795865f / 512.0f)
                         : (-6.2831853071795865f / 512.0f);
    float2 w1;
    __sincosf(sg * (float)lane, &w1.y, &w1.x);
    dft8<INV>(v);
    twiddle8(v, w1);
#pragma unroll
    for (int m = 0; m < 8; ++m) R[FI(8 * lane + m)] = v[m];
    wave_fence();
#pragma unroll
    for (int j = 0; j < 8; ++j) v[j] = R[FI(lane + 64 * j)];
    float2 w1b;
    w1b.x = __shfl(w1.x, lane & 56);
    w1b.y = __shfl(w1.y, lane & 56);
    dft8<INV>(v);
    twiddle8(v, w1b);
    {
        int ob = (lane & 7) + ((lane >> 3) << 6);
#pragma unroll
        for (int m = 0; m < 8; ++m) R[FI(ob + 8 * m)] = v[m];
    }
    wave_fence();
#pragma unroll
    for (int j = 0; j < 8; ++j) v[j] = R[FI(lane + 64 * j)];
    dft8<INV>(v);
}

// K1: real FFT of rows via PAIR-PACKING (round-9 form, unchanged).
__global__ __launch_bounds__(256) void k_row_rfft(const float* __restrict__ x,
                                                  float2* __restrict__ G) {
    __shared__ float2 lds[4][544];
    int lane = threadIdx.x & 63;
    int w = threadIdx.x >> 6;
    int pair = blockIdx.x * 4 + w;
    const float* x0 = x + (size_t)(2 * pair) * 512;
    const float* x1 = x0 + 512;
    float2 v[8];
#pragma unroll
    for (int j = 0; j < 8; ++j)
        v[j] = make_float2(x0[lane + 64 * j], x1[lane + 64 * j]);
    fft512_wave_ip<false>(v, lds[w], lane);
    float2 P[5];
#pragma unroll
    for (int m = 0; m < 5; ++m) {
        int src = (64 - lane) & 63;
        float2 p;
        p.x = __shfl(v[7 - m].x, src);
        p.y = __shfl(v[7 - m].y, src);
        if (lane == 0) p = v[(8 - m) & 7];
        P[m] = p;
    }
    float2* g0 = G + (size_t)(2 * pair) * 257;
    float2* g1 = g0 + 257;
#pragma unroll
    for (int m = 0; m < 4; ++m) {
        int k = lane + 64 * m;
        float2 Z = v[m], Pc = P[m];
        float2 S = make_float2(0.5f * (Z.x + Pc.x), 0.5f * (Z.y - Pc.y));
        float2 D = make_float2(Z.x - Pc.x, Z.y + Pc.y);
        float2 T = make_float2(0.5f * D.y, -0.5f * D.x);
        g0[k] = S;
        g1[k] = T;
    }
    if (lane == 0) {
        float2 Z = v[4], Pc = P[4];
        g0[256] = make_float2(0.5f * (Z.x + Pc.x), 0.5f * (Z.y - Pc.y));
        float2 D = make_float2(Z.x - Pc.x, Z.y + Pc.y);
        g1[256] = make_float2(0.5f * D.y, -0.5f * D.x);
    }
}

// K2: FFT along h for 16 v-columns per block (round-8 form, unchanged).
__global__ __launch_bounds__(1024) void k_col_fft(const float2* __restrict__ G,
                                                  float2* __restrict__ XT) {
    __shared__ float2 tile[16][TSTRIDE];
    int tid = threadIdx.x;
    int l = xcd_remap(blockIdx.x, 272);  // grid = 2176 = 128 nc * 17 vt
    int nc = l / 17;
    int v0 = (l % 17) * 16;
#pragma unroll
    for (int j = 0; j < 8; ++j) {
        int e = tid + 1024 * j;
        int dv = e & 15, h = e >> 4;
        int v = v0 + dv;
        float2 val = make_float2(0.0f, 0.0f);
        if (v < 257) val = G[((size_t)nc * 512 + h) * 257 + v];
        tile[dv][FI(h)] = val;
    }
    __syncthreads();
    int lane = tid & 63, w = tid >> 6;
    float2* R = tile[w];
    float2 vv[8];
#pragma unroll
    for (int j = 0; j < 8; ++j) vv[j] = R[FI(lane + 64 * j)];
    fft512_wave_ip<false>(vv, R, lane);
    int v = v0 + w;
    if (v < 257) {
        float2* dst = XT + ((size_t)nc * 257 + v) * 512;
#pragma unroll
        for (int m = 0; m < 8; ++m) dst[lane + 64 * m] = vv[m];
    }
}

// K3: complex 3x3 conv, v-pair tile, SPLIT-C STAGING: channels staged in two
// halves of 8 -> LDS 16.9 KB -> 8 blocks/CU (32 waves, was 16). The extra
// barriers are hidden by the 8 resident blocks. VGPR 52 fits the 8-wave/EU
// cap (64).
__global__ __launch_bounds__(256, 8) void k_conv(const float2* __restrict__ XT,
                                                 float2* __restrict__ YT,
                                                 const float* __restrict__ wr,
                                                 const float* __restrict__ wi,
                                                 const float* __restrict__ br,
                                                 const float* __restrict__ bi) {
    __shared__ float2 Xs[8 * 4 * 66];  // [c(8)][dvr][uu] = 16896 B
    int tid = threadIdx.x;
    int bid = blockIdx.x;
    int ut = bid & 7;
    int rest = bid >> 3;
    int vt = rest % 129;
    int n = rest / 129;
    int u0 = ut * 64;
    int v0 = vt * 2;

    int lane = tid & 63;
    int wv = __builtin_amdgcn_readfirstlane(tid >> 6);
    int o0 = wv * 4;

    float2 acc[2][4];
#pragma unroll
    for (int oo = 0; oo < 4; ++oo) {
        float2 bv = make_float2(br[o0 + oo], bi[o0 + oo]);
        acc[0][oo] = bv;
        acc[1][oo] = bv;
    }

    for (int half = 0; half < 2; ++half) {
        if (half) __syncthreads();  // protect Xs overwrite
        for (int l = tid; l < 2112; l += 256) {
            int c = l / 264;
            int rem = l - c * 264;
            int dvr = rem / 66;
            int uu = rem - dvr * 66;
            int vg = v0 - 1 + dvr;
            int ug = u0 - 1 + uu;
            int cg = half * 8 + c;
            float2 val = make_float2(0.0f, 0.0f);
            if (vg >= 0 && vg < 257 && ug >= 0 && ug < 512)
                val = XT[(((size_t)n * 16 + cg) * 257 + vg) * 512 + ug];
            Xs[l] = val;
        }
        __syncthreads();

        for (int c = 0; c < 8; ++c) {
            int cg = half * 8 + c;
            float2 xv[4][3];
#pragma unroll
            for (int dvr = 0; dvr < 4; ++dvr) {
                const float2* row = &Xs[(c * 4 + dvr) * 66];
                xv[dvr][0] = row[lane];
                xv[dvr][1] = row[lane + 1];
                xv[dvr][2] = row[lane + 2];
            }
#pragma unroll
            for (int oo = 0; oo < 4; ++oo) {
                const float* wrp = wr + ((size_t)(cg * 16 + o0 + oo)) * 9;
                const float* wip = wi + ((size_t)(cg * 16 + o0 + oo)) * 9;
                float wre[9], wim[9];
#pragma unroll
                for (int t = 0; t < 9; ++t) { wre[t] = wrp[t]; wim[t] = wip[t]; }
#pragma unroll
                for (int kw = 0; kw < 3; ++kw) {
#pragma unroll
                    for (int kh = 0; kh < 3; ++kh) {
                        int t = kh * 3 + kw;
                        int xj = 2 - kh;
                        float2 w = make_float2(wre[t], wim[t]);
                        cmac(acc[0][oo], w, xv[2 - kw][xj]);
                        cmac(acc[1][oo], w, xv[3 - kw][xj]);
                    }
                }
            }
        }
    }

#pragma unroll
    for (int oo = 0; oo < 4; ++oo) {
#pragma unroll
        for (int vv = 0; vv < 2; ++vv) {
            int v = v0 + vv;
            if (v < 257)
                YT[(((size_t)n * 16 + o0 + oo) * 257 + v) * 512 + u0 + lane] =
                    acc[vv][oo];
        }
    }
}

// K4: inverse FFT along u, WAVE-RADIX-8: one wave per (no, v) column,
// coalesced row read/write, in-place FFT in a private LDS row, zero
// barriers (was 5-barrier block Stockham). LDS 17.4 KB.
__global__ __launch_bounds__(256) void k_col_ifft(const float2* __restrict__ YT,
                                                  float2* __restrict__ ZT) {
    __shared__ float2 lds[4][544];
    int lane = threadIdx.x & 63;
    int w = threadIdx.x >> 6;
    int no = blockIdx.x / 65;   // grid = 8320
    int v = (blockIdx.x % 65) * 4 + w;
    if (v >= 257) return;       // no barriers -> uniform wave exit safe
    const float2* src = YT + ((size_t)no * 257 + v) * 512;
    float2 vv[8];
#pragma unroll
    for (int j = 0; j < 8; ++j) vv[j] = src[lane + 64 * j];
    fft512_wave_ip<true>(vv, lds[w], lane);
    const float sc = 1.0f / 512.0f;
    float2* dst = ZT + ((size_t)no * 257 + v) * 512;
#pragma unroll
    for (int m = 0; m < 8; ++m)
        dst[lane + 64 * m] = make_float2(vv[m].x * sc, vv[m].y * sc);
}

// K5: irfft along v via PAIR-UNPACKING (round-9 form, unchanged).
__global__ __launch_bounds__(512) void k_row_irfft(const float2* __restrict__ ZT,
                                                   float* __restrict__ out) {
    __shared__ float2 tile[16][TSTRIDE];
    int tid = threadIdx.x;
    int no = blockIdx.x >> 5;        // grid = 128 * 32
    int h0 = (blockIdx.x & 31) * 16;
#pragma unroll
    for (int j = 0; j < 9; ++j) {
        int e = tid + 512 * j;       // over 257*16 = 4112
        if (e < 4112) {
            int dh = e & 15, vv = e >> 4;
            tile[dh][FI(vv)] = ZT[((size_t)no * 257 + vv) * 512 + h0 + dh];
        }
    }
    __syncthreads();
    int lane = tid & 63, w = tid >> 6;  // pair rows 2w, 2w+1
    float2* Ra = tile[2 * w];
    float2* Rb = tile[2 * w + 1];
    float2 v[8];
#pragma unroll
    for (int m = 0; m < 8; ++m) {
        int i = lane + 64 * m;
        float2 a, b, W;
        if (i <= 256) {
            a = Ra[FI(i)];
            b = Rb[FI(i)];
            if (i == 0 || i == 256) { a.y = 0.0f; b.y = 0.0f; }
            W = make_float2(a.x - b.y, a.y + b.x);
        } else {
            int ii = 512 - i;
            a = Ra[FI(ii)];
            b = Rb[FI(ii)];
            W = make_float2(a.x + b.y, -a.y + b.x);
        }
        v[m] = W;
    }
    fft512_wave_ip<true>(v, Ra, lane);
    const float sc = 1.0f / 512.0f;
    float* d0 = out + ((size_t)no * 512 + h0 + 2 * w) * 512;
    float* d1 = d0 + 512;
#pragma unroll
    for (int m = 0; m < 8; ++m) {
        d0[lane + 64 * m] = v[m].x * sc;
        d1[lane + 64 * m] = v[m].y * sc;
    }
}

extern "C" void kernel_launch(void* const* d_in, const int* in_sizes, int n_in,
                              void* d_out, int out_size, void* d_ws, size_t ws_size,
                              hipStream_t stream) {
    const float* x  = (const float*)d_in[0];
    const float* wr = (const float*)d_in[1];
    const float* wi = (const float*)d_in[2];
    const float* br = (const float*)d_in[3];
    const float* bi = (const float*)d_in[4];
    float* out = (float*)d_out;

    const size_t bufElems = (size_t)128 * 257 * 512;  // complex elements
    float2* A = (float2*)d_ws;
    float2* B = A + bufElems;

    k_row_rfft<<<8192, 256, 0, stream>>>(x, A);                      // x -> G (A)
    k_col_fft<<<128 * 17, 1024, 0, stream>>>(A, B);                  // G -> XT (B)
    k_conv<<<8 * 129 * 8, 256, 0, stream>>>(B, A, wr, wi, br, bi);   // XT -> YT (A)
    k_col_ifft<<<128 * 65, 256, 0, stream>>>(A, B);                  // YT -> ZT (B)
    k_row_irfft<<<128 * 32, 512, 0, stream>>>(B, out);               // ZT -> out
}